// Round 12
// baseline (51.593 us; speedup 1.0000x reference)
//
#include <hip/hip_runtime.h>

#define B 4
#define C 19
#define H 192
#define W 192
#define HW (H * W)
// 40 / ln(2): exp(-40*x) == exp2(-THETA_LOG2E*x)
#define THETA_LOG2E 57.70780163555855f

#define CSEGS 16
#define CSR 12             // rows per segment (column role)
#define NCOLB (B * C * 3)  // 228 column-role blocks (64 cols x 192 rows each)
#define NROWB (B * C * H / 16)  // 912 row-role blocks (16 waves x 1 row)
#define NTHR 1024

// bf16 helpers (RNE)
__device__ __forceinline__ unsigned short f2b(float x) {
    unsigned u = __float_as_uint(x);
    u = (u + 0x7FFFu + ((u >> 16) & 1u)) >> 16;
    return (unsigned short)u;
}
__device__ __forceinline__ float b2f(unsigned short h) {
    return __uint_as_float(((unsigned)h) << 16);
}

// ================= per-iteration kernel: col role + row role in one grid =================
// col role : cs_k[b,c,i,j] = Zc + Sc - f_k        (bf16 out)
// row role : rs_k[b,c,i,j] = Zr + Sr - 2 f_k      (bf16 out)
// MODE 0: f = mask; also compute dcol (col c==0) / drow (row c==0), fp32.
// MODE 1: f = (cs+rs)/(dcol+drow-1); col c==0 blocks also store rD = 1/(dcol+drow-1).
// MODE 2: f = (cs+rs)*rD  (single precomputed stream).
template<int MODE>
__global__ __launch_bounds__(NTHR) void k_iter(const float* __restrict__ mask,
                                               const float* __restrict__ edge,
                                               const unsigned short* __restrict__ csin,
                                               const unsigned short* __restrict__ rsin,
                                               unsigned short* __restrict__ csout,
                                               unsigned short* __restrict__ rsout,
                                               float* __restrict__ dcol,
                                               float* __restrict__ drow,
                                               float* __restrict__ rDg) {
    const int t = threadIdx.x;
    if (blockIdx.x < NCOLB) {
        // ---------------- column role ----------------
        __shared__ float sPf[CSEGS * 64], sQf[CSEGS * 64], sPb[CSEGS * 64], sQb[CSEGS * 64];
        int blk = blockIdx.x;
        int jt = blk % 3, bc = blk / 3, b = bc / C, c = bc % C;
        int jl = t & 63, seg = t >> 6;          // seg 0..15
        int j = jt * 64 + jl, i0 = seg * CSR;

        const float* ep = edge + ((size_t)b * H + i0) * W + j;
        const size_t fb = ((size_t)bc * H + i0) * W + j;
        const size_t db = ((size_t)b * H + i0) * W + j;

        float dr[CSR + 1], fr[CSR];
        #pragma unroll
        for (int r = 0; r < CSR; ++r) dr[r] = exp2f(-THETA_LOG2E * fmaxf(ep[r * W], 0.f));
        dr[CSR] = (seg < CSEGS - 1) ? exp2f(-THETA_LOG2E * fmaxf(ep[CSR * W], 0.f)) : 0.f;

        if (MODE == 0) {
            #pragma unroll
            for (int r = 0; r < CSR; ++r) fr[r] = mask[fb + r * W];
        } else if (MODE == 1) {
            #pragma unroll
            for (int r = 0; r < CSR; ++r) {
                float cs = b2f(csin[fb + r * W]);
                float rs = b2f(rsin[fb + r * W]);
                float rd = 1.f / (dcol[db + r * W] + drow[db + r * W] - 1.f);
                fr[r] = (cs + rs) * rd;
                if (c == 0) rDg[db + r * W] = rd;
            }
        } else {
            #pragma unroll
            for (int r = 0; r < CSR; ++r) {
                float cs = b2f(csin[fb + r * W]);
                float rs = b2f(rsin[fb + r * W]);
                fr[r] = (cs + rs) * rDg[db + r * W];
            }
        }

        float Pf = 1.f, Qf = 0.f, Pb = 1.f, Qb = 0.f;
        #pragma unroll
        for (int r = 0; r < CSR; ++r) { Qf = Qf * dr[r] + fr[r]; Pf *= dr[r]; }
        #pragma unroll
        for (int r = CSR - 1; r >= 0; --r) { Qb = Qb * dr[r + 1] + fr[r]; Pb *= dr[r + 1]; }
        sPf[seg * 64 + jl] = Pf; sQf[seg * 64 + jl] = Qf;
        sPb[seg * 64 + jl] = Pb; sQb[seg * 64 + jl] = Qb;
        __syncthreads();
        if (seg == 0) {          // inclusive prefix transforms
            float P = sPf[jl], Q = sQf[jl];
            for (int s2 = 1; s2 < CSEGS; ++s2) {
                float Pc = sPf[s2 * 64 + jl], Qc = sQf[s2 * 64 + jl];
                Q = Q * Pc + Qc; P = P * Pc;
                sPf[s2 * 64 + jl] = P; sQf[s2 * 64 + jl] = Q;
            }
        } else if (seg == 1) {   // inclusive suffix transforms
            float P = sPb[(CSEGS - 1) * 64 + jl], Q = sQb[(CSEGS - 1) * 64 + jl];
            for (int s2 = CSEGS - 2; s2 >= 0; --s2) {
                float Pc = sPb[s2 * 64 + jl], Qc = sQb[s2 * 64 + jl];
                Q = Q * Pc + Qc; P = P * Pc;
                sPb[s2 * 64 + jl] = P; sQb[s2 * 64 + jl] = Q;
            }
        }
        __syncthreads();
        float z = (seg > 0) ? sQf[(seg - 1) * 64 + jl] : 0.f;
        float s = (seg < CSEGS - 1) ? sQb[(seg + 1) * 64 + jl] : 0.f;
        float zarr[CSR];
        #pragma unroll
        for (int r = 0; r < CSR; ++r) { z = z * dr[r] + fr[r]; zarr[r] = z; }
        #pragma unroll
        for (int r = CSR - 1; r >= 0; --r) {
            s = s * dr[r + 1] + fr[r];
            csout[fb + r * W] = f2b(zarr[r] + s - fr[r]);   // diagonal counted once
        }

        if (MODE == 0 && c == 0) {
            // unit-f column scan -> dcol = Zu + Su - 1 (fp32)
            float Pf2 = 1.f, Qf2 = 0.f, Pb2 = 1.f, Qb2 = 0.f;
            #pragma unroll
            for (int r = 0; r < CSR; ++r) { Qf2 = Qf2 * dr[r] + 1.f; Pf2 *= dr[r]; }
            #pragma unroll
            for (int r = CSR - 1; r >= 0; --r) { Qb2 = Qb2 * dr[r + 1] + 1.f; Pb2 *= dr[r + 1]; }
            __syncthreads();
            sPf[seg * 64 + jl] = Pf2; sQf[seg * 64 + jl] = Qf2;
            sPb[seg * 64 + jl] = Pb2; sQb[seg * 64 + jl] = Qb2;
            __syncthreads();
            if (seg == 0) {
                float P = sPf[jl], Q = sQf[jl];
                for (int s2 = 1; s2 < CSEGS; ++s2) {
                    float Pc = sPf[s2 * 64 + jl], Qc = sQf[s2 * 64 + jl];
                    Q = Q * Pc + Qc; P = P * Pc;
                    sPf[s2 * 64 + jl] = P; sQf[s2 * 64 + jl] = Q;
                }
            } else if (seg == 1) {
                float P = sPb[(CSEGS - 1) * 64 + jl], Q = sQb[(CSEGS - 1) * 64 + jl];
                for (int s2 = CSEGS - 2; s2 >= 0; --s2) {
                    float Pc = sPb[s2 * 64 + jl], Qc = sQb[s2 * 64 + jl];
                    Q = Q * Pc + Qc; P = P * Pc;
                    sPb[s2 * 64 + jl] = P; sQb[s2 * 64 + jl] = Q;
                }
            }
            __syncthreads();
            float zu = (seg > 0) ? sQf[(seg - 1) * 64 + jl] : 0.f;
            float su = (seg < CSEGS - 1) ? sQb[(seg + 1) * 64 + jl] : 0.f;
            #pragma unroll
            for (int r = 0; r < CSR; ++r) { zu = zu * dr[r] + 1.f; zarr[r] = zu; }
            #pragma unroll
            for (int r = CSR - 1; r >= 0; --r) {
                su = su * dr[r + 1] + 1.f;
                dcol[db + r * W] = zarr[r] + su - 1.f;
            }
        }
    } else {
        // ---------------- row role: one row per wave ----------------
        int rblk = blockIdx.x - NCOLB;
        int wave = t >> 6, lane = t & 63;
        int rr = rblk * 16 + wave;             // 0 .. B*C*H-1
        int i = rr % H;
        int c = (rr / H) % C;
        int b = rr / (H * C);
        const size_t rb = ((size_t)(b * C + c) * H + i) * W;
        const int db = (b * H + i) * W;
        const int s0 = 3 * lane;

        float e0 = edge[db + s0], e1 = edge[db + s0 + 1], e2 = edge[db + s0 + 2];
        float d0 = exp2f(-THETA_LOG2E * fmaxf(e0, 0.f));
        float d1 = exp2f(-THETA_LOG2E * fmaxf(e1, 0.f));
        float d2 = exp2f(-THETA_LOG2E * fmaxf(e2, 0.f));
        float d3 = 0.f;
        if (lane < 63) {
            float e3 = edge[db + s0 + 3];
            d3 = exp2f(-THETA_LOG2E * fmaxf(e3, 0.f));
        }

        float f0, f1, f2;
        if (MODE == 0) {
            f0 = mask[rb + s0]; f1 = mask[rb + s0 + 1]; f2 = mask[rb + s0 + 2];
        } else if (MODE == 1) {
            float rd0 = 1.f / (dcol[db + s0]     + drow[db + s0]     - 1.f);
            float rd1 = 1.f / (dcol[db + s0 + 1] + drow[db + s0 + 1] - 1.f);
            float rd2 = 1.f / (dcol[db + s0 + 2] + drow[db + s0 + 2] - 1.f);
            f0 = (b2f(csin[rb + s0])     + b2f(rsin[rb + s0]))     * rd0;
            f1 = (b2f(csin[rb + s0 + 1]) + b2f(rsin[rb + s0 + 1])) * rd1;
            f2 = (b2f(csin[rb + s0 + 2]) + b2f(rsin[rb + s0 + 2])) * rd2;
        } else {
            f0 = (b2f(csin[rb + s0])     + b2f(rsin[rb + s0]))     * rDg[db + s0];
            f1 = (b2f(csin[rb + s0 + 1]) + b2f(rsin[rb + s0 + 1])) * rDg[db + s0 + 1];
            f2 = (b2f(csin[rb + s0 + 2]) + b2f(rsin[rb + s0 + 2])) * rDg[db + s0 + 2];
        }

        // forward scan: Z[s] = d[s]*Z[s-1] + f[s]
        float P = d0 * d1 * d2;
        float Q = (f0 * d1 + f1) * d2 + f2;
        #pragma unroll
        for (int off = 1; off < 64; off <<= 1) {
            float Pp = __shfl_up(P, off);
            float Qp = __shfl_up(Q, off);
            if (lane >= off) { Q = Qp * P + Q; P = Pp * P; }
        }
        float zin = __shfl_up(Q, 1);
        if (lane == 0) zin = 0.f;
        float zA = zin * d0 + f0;
        float zB = zA * d1 + f1;
        float zC = zB * d2 + f2;

        // backward scan: Sf[s] = d[s+1]*Sf[s+1] + f[s]
        float Pb = d3 * d2 * d1;
        float Qb = (f2 * d2 + f1) * d1 + f0;
        #pragma unroll
        for (int off = 1; off < 64; off <<= 1) {
            float Pp = __shfl_down(Pb, off);
            float Qp = __shfl_down(Qb, off);
            if (lane < 64 - off) { Qb = Qp * Pb + Qb; Pb = Pp * Pb; }
        }
        float sin_ = __shfl_down(Qb, 1);
        if (lane == 63) sin_ = 0.f;
        float sC = sin_ * d3 + f2;
        float sB = sC * d2 + f1;
        float sA = sB * d1 + f0;

        rsout[rb + s0]     = f2b(zA + sA - 2.f * f0);
        rsout[rb + s0 + 1] = f2b(zB + sB - 2.f * f1);
        rsout[rb + s0 + 2] = f2b(zC + sC - 2.f * f2);

        if (MODE == 0 && c == 0) {
            // unit-f row scan -> drow = Zu + Su - 1 (fp32)
            float Pu = d0 * d1 * d2;
            float Qu = d1 * d2 + d2 + 1.f;
            #pragma unroll
            for (int off = 1; off < 64; off <<= 1) {
                float Pp = __shfl_up(Pu, off);
                float Qp = __shfl_up(Qu, off);
                if (lane >= off) { Qu = Qp * Pu + Qu; Pu = Pp * Pu; }
            }
            float zuin = __shfl_up(Qu, 1);
            if (lane == 0) zuin = 0.f;
            float zuA = zuin * d0 + 1.f;
            float zuB = zuA * d1 + 1.f;
            float zuC = zuB * d2 + 1.f;

            float Pub = d3 * d2 * d1;
            float Qub = d2 * d1 + d1 + 1.f;
            #pragma unroll
            for (int off = 1; off < 64; off <<= 1) {
                float Pp = __shfl_down(Pub, off);
                float Qp = __shfl_down(Qub, off);
                if (lane < 64 - off) { Qub = Qp * Pub + Qub; Pub = Pp * Pub; }
            }
            float suin = __shfl_down(Qub, 1);
            if (lane == 63) suin = 0.f;
            float suC = suin * d3 + 1.f;
            float suB = suC * d2 + 1.f;
            float suA = suB * d1 + 1.f;

            drow[db + s0]     = zuA + suA - 1.f;
            drow[db + s0 + 1] = zuB + suB - 1.f;
            drow[db + s0 + 2] = zuC + suC - 1.f;
        }
    }
}

// ================= final combine: out = (cs + rs) * rD =================
__global__ __launch_bounds__(256) void k_comb(const unsigned short* __restrict__ cs,
                                              const unsigned short* __restrict__ rs,
                                              const float* __restrict__ rDg,
                                              float* __restrict__ out) {
    int idx4 = (blockIdx.x * 256 + threadIdx.x) * 4;    // B*C*HW / 4 threads
    int bc = idx4 / HW;
    int rem = idx4 - bc * HW;
    int b = bc / C;
    size_t db = (size_t)b * HW + rem;
    uint2 csu = *(const uint2*)(cs + idx4);
    uint2 rsu = *(const uint2*)(rs + idx4);
    float4 rd = *(const float4*)(rDg + db);
    float4 o;
    o.x = (b2f((unsigned short)(csu.x & 0xffff)) + b2f((unsigned short)(rsu.x & 0xffff))) * rd.x;
    o.y = (b2f((unsigned short)(csu.x >> 16))    + b2f((unsigned short)(rsu.x >> 16)))    * rd.y;
    o.z = (b2f((unsigned short)(csu.y & 0xffff)) + b2f((unsigned short)(rsu.y & 0xffff))) * rd.z;
    o.w = (b2f((unsigned short)(csu.y >> 16))    + b2f((unsigned short)(rsu.y >> 16)))    * rd.w;
    *(float4*)(out + idx4) = o;
}

extern "C" void kernel_launch(void* const* d_in, const int* in_sizes, int n_in,
                              void* d_out, int out_size, void* d_ws, size_t ws_size,
                              hipStream_t stream) {
    const float* mask = (const float*)d_in[0];
    const float* edge = (const float*)d_in[1];
    float* out = (float*)d_out;

    float* dcol = (float*)d_ws;                         // [B,H,W] fp32
    float* drow = dcol + (size_t)B * HW;                // [B,H,W] fp32
    float* rDg  = drow + (size_t)B * HW;                // [B,H,W] fp32
    unsigned short* csA = (unsigned short*)(rDg + (size_t)B * HW);
    unsigned short* rsA = csA + (size_t)B * C * HW;     // bf16 [B*C,H,W] each
    unsigned short* csB = rsA + (size_t)B * C * HW;
    unsigned short* rsB = csB + (size_t)B * C * HW;

    const int grid = NCOLB + NROWB;   // 228 + 912 = 1140

    // A0: f0 = mask -> csA, rsA  (+ dcol, drow)
    k_iter<0><<<grid, NTHR, 0, stream>>>(mask, edge, nullptr, nullptr, csA, rsA, dcol, drow, nullptr);
    // A1: fold A -> B  (+ rD store by col c==0 blocks)
    k_iter<1><<<grid, NTHR, 0, stream>>>(nullptr, edge, csA, rsA, csB, rsB, dcol, drow, rDg);
    // A2: fold B -> A  (reads precomputed rD)
    k_iter<2><<<grid, NTHR, 0, stream>>>(nullptr, edge, csB, rsB, csA, rsA, nullptr, nullptr, rDg);
    // final combine -> out
    k_comb<<<(B * C * HW) / (4 * 256), 256, 0, stream>>>(csA, rsA, rDg, out);
}